// Round 6
// baseline (252.914 us; speedup 1.0000x reference)
//
#include <hip/hip_runtime.h>
#include <math.h>

// Problem constants
#define BB 4
#define TT 1024
#define EE 1024
#define HH 16
#define DD 64
#define KDIM 1024
#define N_HS (4096 * 1024)     // hidden_states elems (also ctx)
#define N_W  (1024 * 1024)     // one weight matrix elems
#define NQKV (BB * HH * TT * DD)
#define NMASK (BB * TT * TT)

typedef _Float16 f16x8 __attribute__((ext_vector_type(8)));   // 4 VGPRs
typedef float    f32x4 __attribute__((ext_vector_type(4)));

// fp32 -> fp16 bits, RTNE
__device__ __forceinline__ unsigned short f2h(float x) {
    _Float16 h = (_Float16)x;
    return __builtin_bit_cast(unsigned short, h);
}
// split x = hi + lo, both fp16
__device__ __forceinline__ void split_h(float x, unsigned short& hi, unsigned short& lo) {
    _Float16 h = (_Float16)x;
    hi = __builtin_bit_cast(unsigned short, h);
    lo = f2h(x - (float)h);
}

// async global->LDS 16B copy
__device__ __forceinline__ void gload16(const void* g, void* l) {
    __builtin_amdgcn_global_load_lds(
        (const __attribute__((address_space(1))) void*)g,
        (__attribute__((address_space(3))) void*)l, 16, 0, 0);
}

// ---------------------------------------------------------------------------
// Elementwise fp32 -> fp16 convert: hs + 4 weights + mask.
// ws layout (ushort units):
//   [0]                hs (N_HS)               (aliased as ctx_hi later)
//   [N_HS]             wq, wk, wv, wo          (N_W each)
//   [N_HS+4N_W]        q, k                    (NQKV each), then vT (NQKV, [B,H,D,T])
//   [.. +3NQKV]        ctx_lo                  (N_HS)
//   [.. +N_HS]         mask fp16               (NMASK)
// ---------------------------------------------------------------------------
__global__ __launch_bounds__(256)
void split_kernel(const float* __restrict__ hs,
                  const float* __restrict__ Wq, const float* __restrict__ Wk,
                  const float* __restrict__ Wv, const float* __restrict__ Wo,
                  const float* __restrict__ maskp,
                  unsigned short* __restrict__ ws,
                  unsigned short* __restrict__ maskh)
{
    const int u = blockIdx.x * 256 + threadIdx.x;   // float4 id, 3,145,728 total
    const float* src;
    unsigned short* dst;
    if (u < (N_HS / 4)) {
        src = hs + (size_t)u * 4;
        dst = ws + (size_t)u * 4;
    } else if (u < (N_HS / 4) + N_W) {              // 4 weights = 4*(N_W/4) float4
        int v = u - N_HS / 4;
        int wsel = v >> 18;             // N_W/4 = 262144 float4 per weight
        int wo   = v & 0x3FFFF;
        const float* Wsrc = (wsel == 0) ? Wq : (wsel == 1) ? Wk : (wsel == 2) ? Wv : Wo;
        src = Wsrc + (size_t)wo * 4;
        dst = ws + (size_t)N_HS + (size_t)wsel * N_W + (size_t)wo * 4;
    } else {
        int v = u - (N_HS / 4) - N_W;
        src = maskp + (size_t)v * 4;
        dst = maskh + (size_t)v * 4;
    }
    float4 x = *(const float4*)src;
    ushort4 h4;
    h4.x = f2h(x.x); h4.y = f2h(x.y); h4.z = f2h(x.z); h4.w = f2h(x.w);
    *(ushort4*)dst = h4;
}

// ---------------------------------------------------------------------------
// QKV projection, single-fp16 MFMA. q/k scattered to [B,H,T,D]; V written
// DIRECTLY TRANSPOSED to [B,H,D,T] (ushort4 over 4 consecutive t).
// ---------------------------------------------------------------------------
__global__ __launch_bounds__(256)
void qkv_kernel(const unsigned short* __restrict__ hsp,
                const unsigned short* __restrict__ wqp,
                const float* __restrict__ bq, const float* __restrict__ bk,
                const float* __restrict__ bv,
                unsigned short* __restrict__ qkvb)
{
    __shared__ unsigned short Ah[128 * 32], Bh[128 * 32];

    const int widx  = blockIdx.x >> 3;
    const int nbase = (blockIdx.x & 7) * 128;
    const int mbase = blockIdx.y * 128;
    const unsigned short* Wp = wqp + (size_t)widx * N_W;
    const float* bias = (widx == 0) ? bq : (widx == 1) ? bk : bv;
    const float scale = (widx == 0) ? 0.125f : 1.0f;   // D^-0.5

    const int tid  = threadIdx.x;
    const int w    = tid >> 6;
    const int lane = tid & 63;
    const int quad = lane >> 4;
    const int l16  = lane & 15;
    const int wm   = (w >> 1) * 64;
    const int wn   = (w & 1) * 64;

    f32x4 acc[4][4];
#pragma unroll
    for (int i = 0; i < 4; i++)
#pragma unroll
        for (int j = 0; j < 4; j++) acc[i][j] = (f32x4)0.f;

#pragma unroll 1
    for (int kt = 0; kt < KDIM; kt += 32) {
        __syncthreads();
#pragma unroll
        for (int i = 0; i < 2; i++) {
            int u = tid + i * 256;              // 16B chunk id, 512/plane
            int r = u >> 2, c = u & 3;
            int q = c ^ ((r >> 1) & 3);
            gload16(hsp + (size_t)(mbase + r) * KDIM + kt + q * 8, &Ah[u * 8]);
            gload16(Wp  + (size_t)(nbase + r) * KDIM + kt + q * 8, &Bh[u * 8]);
        }
        __syncthreads();

        f16x8 af[4], bfr[4];
#pragma unroll
        for (int i = 0; i < 4; i++) {
            int r = wm + i * 16 + l16;
            af[i] = *(const f16x8*)&Ah[(r * 4 + (quad ^ ((r >> 1) & 3))) * 8];
        }
#pragma unroll
        for (int j = 0; j < 4; j++) {
            int r = wn + j * 16 + l16;
            bfr[j] = *(const f16x8*)&Bh[(r * 4 + (quad ^ ((r >> 1) & 3))) * 8];
        }
#pragma unroll
        for (int i = 0; i < 4; i++)
#pragma unroll
            for (int j = 0; j < 4; j++)
                acc[i][j] = __builtin_amdgcn_mfma_f32_16x16x32_f16(af[i], bfr[j], acc[i][j], 0, 0, 0);
    }

    if (widx == 2) {
        // V: write transposed [B,H,D,T], 4 consecutive t per ushort4
        unsigned short* vtp = qkvb + 2 * (size_t)NQKV;
#pragma unroll
        for (int j = 0; j < 4; j++) {
            int n = nbase + wn + j * 16 + l16;
            int h = n >> 6, d = n & 63;
            float bj = bias[n];
#pragma unroll
            for (int i = 0; i < 4; i++) {
                int m = mbase + wm + i * 16 + quad * 4;
                int b = m >> 10, t0 = m & 1023;
                ushort4 pk;
                pk.x = f2h(acc[i][j][0] + bj);
                pk.y = f2h(acc[i][j][1] + bj);
                pk.z = f2h(acc[i][j][2] + bj);
                pk.w = f2h(acc[i][j][3] + bj);
                *(ushort4*)(vtp + ((size_t)(b * HH + h) * DD + d) * TT + t0) = pk;
            }
        }
    } else {
        unsigned short* dst = qkvb + (size_t)widx * NQKV;
#pragma unroll
        for (int j = 0; j < 4; j++) {
            int n = nbase + wn + j * 16 + l16;
            int h = n >> 6, d = n & 63;
            float bj = bias[n];
#pragma unroll
            for (int i = 0; i < 4; i++)
#pragma unroll
                for (int rr = 0; rr < 4; rr++) {
                    int m = mbase + wm + i * 16 + quad * 4 + rr;
                    int b = m >> 10, t = m & 1023;
                    dst[(((size_t)(b * HH + h) * TT + t) * DD + d)] =
                        f2h((acc[i][j][rr] + bj) * scale);
                }
        }
    }
}

// ---------------------------------------------------------------------------
// Out projection, 2-term fp16 (unchanged).
// ---------------------------------------------------------------------------
__global__ __launch_bounds__(256)
void outproj_kernel(const unsigned short* __restrict__ ctxh,
                    const unsigned short* __restrict__ ctxl,
                    const unsigned short* __restrict__ wop,
                    const float* __restrict__ bo, float* __restrict__ out)
{
    __shared__ unsigned short Ach[64 * 32], Acl[64 * 32], Bh[128 * 32];

    const int nbase = blockIdx.x * 128;
    const int mbase = blockIdx.y * 64;

    const int tid  = threadIdx.x;
    const int w    = tid >> 6;
    const int lane = tid & 63;
    const int quad = lane >> 4;
    const int l16  = lane & 15;
    const int wm   = (w >> 1) * 32;
    const int wn   = (w & 1) * 64;

    f32x4 acc[2][4];
#pragma unroll
    for (int i = 0; i < 2; i++)
#pragma unroll
        for (int j = 0; j < 4; j++) acc[i][j] = (f32x4)0.f;

#pragma unroll 1
    for (int kt = 0; kt < KDIM; kt += 32) {
        __syncthreads();
        {
            int r = tid >> 2, c = tid & 3;
            int q = c ^ ((r >> 1) & 3);
            size_t ga = (size_t)(mbase + r) * KDIM + kt + q * 8;
            gload16(ctxh + ga, &Ach[tid * 8]);
            gload16(ctxl + ga, &Acl[tid * 8]);
        }
#pragma unroll
        for (int i = 0; i < 2; i++) {
            int u = tid + i * 256;
            int r = u >> 2, c = u & 3;
            int q = c ^ ((r >> 1) & 3);
            gload16(wop + (size_t)(nbase + r) * KDIM + kt + q * 8, &Bh[u * 8]);
        }
        __syncthreads();

        f16x8 ah[2], al[2], bfr[4];
#pragma unroll
        for (int i = 0; i < 2; i++) {
            int r = wm + i * 16 + l16;
            int slot = (r * 4 + (quad ^ ((r >> 1) & 3))) * 8;
            ah[i] = *(const f16x8*)&Ach[slot];
            al[i] = *(const f16x8*)&Acl[slot];
        }
#pragma unroll
        for (int j = 0; j < 4; j++) {
            int r = wn + j * 16 + l16;
            bfr[j] = *(const f16x8*)&Bh[(r * 4 + (quad ^ ((r >> 1) & 3))) * 8];
        }
#pragma unroll
        for (int i = 0; i < 2; i++)
#pragma unroll
            for (int j = 0; j < 4; j++) {
                acc[i][j] = __builtin_amdgcn_mfma_f32_16x16x32_f16(ah[i], bfr[j], acc[i][j], 0, 0, 0);
                acc[i][j] = __builtin_amdgcn_mfma_f32_16x16x32_f16(al[i], bfr[j], acc[i][j], 0, 0, 0);
            }
    }

#pragma unroll
    for (int j = 0; j < 4; j++) {
        int n = nbase + wn + j * 16 + l16;
        float bj = bo[n];
#pragma unroll
        for (int i = 0; i < 2; i++)
#pragma unroll
            for (int rr = 0; rr < 4; rr++) {
                int m = mbase + wm + i * 16 + quad * 4 + rr;
                out[(size_t)m * EE + n] = acc[i][j][rr] + bj;
            }
    }
}

// ---------------------------------------------------------------------------
// MFMA flash attention, fp16, single-barrier double-buffered K/V pipeline.
// Per iter: barrier (drains DMA issued last iter) -> issue DMA for tile i+1
// into other buffer -> compute tile i. DMA overlaps the whole compute phase.
// Ps XOR-swizzled (no pad). LDS = 2*8K(K) + 2*8K(V) + 8K(Ps) = 40 KB ->
// exactly 4 blocks/CU (matches the 1024-block grid's 4/CU).
// ---------------------------------------------------------------------------
__global__ __launch_bounds__(256)
void attn_kernel(const unsigned short* __restrict__ qp_, const unsigned short* __restrict__ kp_,
                 const unsigned short* __restrict__ vtp_,
                 const unsigned short* __restrict__ maskh,
                 unsigned short* __restrict__ ctxh, unsigned short* __restrict__ ctxl)
{
    __shared__ unsigned short Ks[2][64 * 64];  // rows kv, chunk-swizzled
    __shared__ unsigned short Vt[2][64 * 64];  // rows d, cols kv, chunk-swizzled
    __shared__ unsigned short Ps[64 * 64];     // XOR-swizzled

    const int bh = blockIdx.y;
    const int b  = bh >> 4;
    const int h  = bh & 15;
    const int m0 = blockIdx.x * 64;
    const size_t hoff = (size_t)bh * TT * DD;
    const unsigned short* qhp = qp_ + hoff;
    const unsigned short* khp = kp_ + hoff;
    const unsigned short* vtp = vtp_ + hoff;   // [D][T] for this bh
    const _Float16* mb = (const _Float16*)(maskh + (size_t)b * TT * TT);

    const int tid  = threadIdx.x;
    const int w    = tid >> 6;
    const int lane = tid & 63;
    const int quad = lane >> 4;
    const int l16  = lane & 15;

    auto stage = [&](int n0s, int bb) {
#pragma unroll
        for (int i = 0; i < 2; i++) {
            int u = tid + i * 256;
            int r = u >> 3, cp = u & 7;
            int c = cp ^ (r & 7);
            gload16(khp + (size_t)(n0s + r) * DD + c * 8, &Ks[bb][u * 8]);
            gload16(vtp + (size_t)r * TT + n0s + c * 8,   &Vt[bb][u * 8]);
        }
    };

    // Q fragments, resident whole kernel (A-frag: m=l16, k=s*32+quad*8+j)
    f16x8 qf[2];
#pragma unroll
    for (int s = 0; s < 2; s++)
        qf[s] = *(const f16x8*)(qhp + (size_t)(m0 + w * 16 + l16) * DD + s * 32 + quad * 8);

    f32x4 o[4];
    float m_i[4], l_i[4];
#pragma unroll
    for (int t = 0; t < 4; t++) o[t] = (f32x4)0.f;
#pragma unroll
    for (int r = 0; r < 4; r++) { m_i[r] = -INFINITY; l_i[r] = 0.f; }

    stage(0, 0);   // preload tile 0

#pragma unroll 1
    for (int it = 0; it < TT / 64; it++) {
        const int n0  = it * 64;
        const int cur = it & 1;

        __syncthreads();   // drains last-issued DMA (vmcnt 0) + buffer safety
        if (it + 1 < TT / 64) stage(n0 + 64, 1 - cur);

        // mask loads (fp16) — issued now, consumed after QK^T
        _Float16 mreg[4][4];
#pragma unroll
        for (int t = 0; t < 4; t++)
#pragma unroll
            for (int r = 0; r < 4; r++)
                mreg[t][r] = mb[(size_t)(m0 + w * 16 + quad * 4 + r) * TT + n0 + 16 * t + l16];

        // S = Q.K^T
        f32x4 st[4];
#pragma unroll
        for (int t = 0; t < 4; t++) st[t] = (f32x4)0.f;
#pragma unroll
        for (int s = 0; s < 2; s++)
#pragma unroll
            for (int t = 0; t < 4; t++) {
                int R = 16 * t + l16;
                const f16x8 kf = *(const f16x8*)&Ks[cur][(R * 8 + ((s * 4 + quad) ^ (R & 7))) * 8];
                st[t] = __builtin_amdgcn_mfma_f32_16x16x32_f16(qf[s], kf, st[t], 0, 0, 0);
            }
        // + mask
#pragma unroll
        for (int t = 0; t < 4; t++)
#pragma unroll
            for (int r = 0; r < 4; r++)
                st[t][r] += (float)mreg[t][r];

        // online softmax (fp32)
        float rm[4], rs[4], alpha[4];
#pragma unroll
        for (int r = 0; r < 4; r++)
            rm[r] = fmaxf(fmaxf(st[0][r], st[1][r]), fmaxf(st[2][r], st[3][r]));
#pragma unroll
        for (int mky = 1; mky < 16; mky <<= 1)
#pragma unroll
            for (int r = 0; r < 4; r++)
                rm[r] = fmaxf(rm[r], __shfl_xor(rm[r], mky));
#pragma unroll
        for (int r = 0; r < 4; r++) {
            float mn = fmaxf(m_i[r], rm[r]);
            alpha[r] = __expf(m_i[r] - mn);
            m_i[r]   = mn;
            rs[r]    = 0.f;
        }
#pragma unroll
        for (int t = 0; t < 4; t++)
#pragma unroll
            for (int r = 0; r < 4; r++) {
                float p = __expf(st[t][r] - m_i[r]);
                st[t][r] = p;
                rs[r] += p;
            }
#pragma unroll
        for (int mky = 1; mky < 16; mky <<= 1)
#pragma unroll
            for (int r = 0; r < 4; r++)
                rs[r] += __shfl_xor(rs[r], mky);
#pragma unroll
        for (int r = 0; r < 4; r++)
            l_i[r] = l_i[r] * alpha[r] + rs[r];
#pragma unroll
        for (int t = 0; t < 4; t++)
#pragma unroll
            for (int r = 0; r < 4; r++)
                o[t][r] *= alpha[r];

        // P (C-layout) -> fp16 LDS, XOR-swizzled; same-wave RAW via lgkmcnt
#pragma unroll
        for (int t = 0; t < 4; t++)
#pragma unroll
            for (int r = 0; r < 4; r++) {
                int R = w * 16 + quad * 4 + r;
                int j = 16 * t + l16;
                Ps[R * 64 + (((j >> 3) ^ (R & 7)) * 8) + (j & 7)] = f2h(st[t][r]);
            }

        // O += P.V
#pragma unroll
        for (int s = 0; s < 2; s++) {
            int Rr = w * 16 + l16;
            const f16x8 pf = *(const f16x8*)&Ps[Rr * 64 + (((s * 4 + quad) ^ (Rr & 7)) * 8)];
#pragma unroll
            for (int t = 0; t < 4; t++) {
                int R = 16 * t + l16;
                const f16x8 vf = *(const f16x8*)&Vt[cur][(R * 8 + ((s * 4 + quad) ^ (R & 7))) * 8];
                o[t] = __builtin_amdgcn_mfma_f32_16x16x32_f16(pf, vf, o[t], 0, 0, 0);
            }
        }
    }

    // epilogue: normalize, split fp16 hi/lo ctx planes [B,T,E]
#pragma unroll
    for (int r = 0; r < 4; r++) {
        float inv = 1.0f / l_i[r];
        int m = m0 + w * 16 + quad * 4 + r;
#pragma unroll
        for (int t = 0; t < 4; t++) {
            float val = o[t][r] * inv;
            unsigned short hi, lo;
            split_h(val, hi, lo);
            size_t off = (size_t)(b * TT + m) * EE + h * DD + 16 * t + l16;
            ctxh[off] = hi;
            ctxl[off] = lo;
        }
    }
}

// ---------------------------------------------------------------------------
extern "C" void kernel_launch(void* const* d_in, const int* in_sizes, int n_in,
                              void* d_out, int out_size, void* d_ws, size_t ws_size,
                              hipStream_t stream)
{
    const float* hs   = (const float*)d_in[0];
    const float* mask = (const float*)d_in[1];
    const float* Wq   = (const float*)d_in[2];
    const float* bq   = (const float*)d_in[3];
    const float* Wk   = (const float*)d_in[4];
    const float* bk   = (const float*)d_in[5];
    const float* Wv   = (const float*)d_in[6];
    const float* bv   = (const float*)d_in[7];
    const float* Wo   = (const float*)d_in[8];
    const float* bo   = (const float*)d_in[9];
    float* out = (float*)d_out;

    unsigned short* ws    = (unsigned short*)d_ws;
    unsigned short* hsp   = ws;                                 // fp16 hs (-> ctx_hi)
    unsigned short* wqp   = ws + (size_t)N_HS;                  // wq,wk,wv,wo
    unsigned short* wop   = wqp + 3 * (size_t)N_W;
    unsigned short* qkvb  = wqp + 4 * (size_t)N_W;              // q, k, vT
    unsigned short* qp    = qkvb;
    unsigned short* kp    = qp + (size_t)NQKV;
    unsigned short* vtp   = kp + (size_t)NQKV;                  // V^T [B,H,D,T]
    unsigned short* ctxl  = vtp + (size_t)NQKV;
    unsigned short* maskh = ctxl + (size_t)N_HS;
    unsigned short* ctxh  = ws;                                 // alias hs (dead after qkv)

    split_kernel<<<12288, 256, 0, stream>>>(hs, Wq, Wk, Wv, Wo, mask, ws, maskh);
    qkv_kernel<<<dim3(24, 32), 256, 0, stream>>>(hsp, wqp, bq, bk, bv, qkvb);
    attn_kernel<<<dim3(TT / 64, BB * HH), 256, 0, stream>>>(qp, kp, vtp, maskh, ctxh, ctxl);
    outproj_kernel<<<dim3(8, 64), 256, 0, stream>>>(ctxh, ctxl, wop, bo, out);
}

// Round 7
// 244.294 us; speedup vs baseline: 1.0353x; 1.0353x over previous
//
#include <hip/hip_runtime.h>
#include <math.h>

// Problem constants
#define BB 4
#define TT 1024
#define EE 1024
#define HH 16
#define DD 64
#define KDIM 1024
#define N_HS (4096 * 1024)     // hidden_states elems (also ctx)
#define N_W  (1024 * 1024)     // one weight matrix elems
#define NQKV (BB * HH * TT * DD)
#define NMASK (BB * TT * TT)

typedef _Float16 f16x8 __attribute__((ext_vector_type(8)));   // 4 VGPRs
typedef float    f32x4 __attribute__((ext_vector_type(4)));

// fp32 -> fp16 bits, RTNE
__device__ __forceinline__ unsigned short f2h(float x) {
    _Float16 h = (_Float16)x;
    return __builtin_bit_cast(unsigned short, h);
}
// split x = hi + lo, both fp16
__device__ __forceinline__ void split_h(float x, unsigned short& hi, unsigned short& lo) {
    _Float16 h = (_Float16)x;
    hi = __builtin_bit_cast(unsigned short, h);
    lo = f2h(x - (float)h);
}

// async global->LDS 16B copy
__device__ __forceinline__ void gload16(const void* g, void* l) {
    __builtin_amdgcn_global_load_lds(
        (const __attribute__((address_space(1))) void*)g,
        (__attribute__((address_space(3))) void*)l, 16, 0, 0);
}

// ---------------------------------------------------------------------------
// Elementwise fp32 -> fp16 convert: hs + 4 weights + mask.
// ws layout (ushort units):
//   [0]                hs (N_HS)               (aliased as ctx_hi later)
//   [N_HS]             wq, wk, wv, wo          (N_W each)
//   [N_HS+4N_W]        q, k (NQKV each), vT (NQKV, [B,H,D,T])
//   [.. +3NQKV]        ctx_lo                  (N_HS)
//   [.. +N_HS]         mask fp16               (NMASK)
// ---------------------------------------------------------------------------
__global__ __launch_bounds__(256)
void split_kernel(const float* __restrict__ hs,
                  const float* __restrict__ Wq, const float* __restrict__ Wk,
                  const float* __restrict__ Wv, const float* __restrict__ Wo,
                  const float* __restrict__ maskp,
                  unsigned short* __restrict__ ws,
                  unsigned short* __restrict__ maskh)
{
    const int u = blockIdx.x * 256 + threadIdx.x;   // float4 id, 3,145,728 total
    const float* src;
    unsigned short* dst;
    if (u < (N_HS / 4)) {
        src = hs + (size_t)u * 4;
        dst = ws + (size_t)u * 4;
    } else if (u < (N_HS / 4) + N_W) {              // 4 weights = 4*(N_W/4) float4
        int v = u - N_HS / 4;
        int wsel = v >> 18;             // N_W/4 = 262144 float4 per weight
        int wo   = v & 0x3FFFF;
        const float* Wsrc = (wsel == 0) ? Wq : (wsel == 1) ? Wk : (wsel == 2) ? Wv : Wo;
        src = Wsrc + (size_t)wo * 4;
        dst = ws + (size_t)N_HS + (size_t)wsel * N_W + (size_t)wo * 4;
    } else {
        int v = u - (N_HS / 4) - N_W;
        src = maskp + (size_t)v * 4;
        dst = maskh + (size_t)v * 4;
    }
    float4 x = *(const float4*)src;
    ushort4 h4;
    h4.x = f2h(x.x); h4.y = f2h(x.y); h4.z = f2h(x.z); h4.w = f2h(x.w);
    *(ushort4*)dst = h4;
}

// ---------------------------------------------------------------------------
// QKV projection, single-fp16 MFMA. q/k scattered to [B,H,T,D]; V written
// DIRECTLY TRANSPOSED to [B,H,D,T] (ushort4 over 4 consecutive t).
// ---------------------------------------------------------------------------
__global__ __launch_bounds__(256)
void qkv_kernel(const unsigned short* __restrict__ hsp,
                const unsigned short* __restrict__ wqp,
                const float* __restrict__ bq, const float* __restrict__ bk,
                const float* __restrict__ bv,
                unsigned short* __restrict__ qkvb)
{
    __shared__ unsigned short Ah[128 * 32], Bh[128 * 32];

    const int widx  = blockIdx.x >> 3;
    const int nbase = (blockIdx.x & 7) * 128;
    const int mbase = blockIdx.y * 128;
    const unsigned short* Wp = wqp + (size_t)widx * N_W;
    const float* bias = (widx == 0) ? bq : (widx == 1) ? bk : bv;
    const float scale = (widx == 0) ? 0.125f : 1.0f;   // D^-0.5

    const int tid  = threadIdx.x;
    const int w    = tid >> 6;
    const int lane = tid & 63;
    const int quad = lane >> 4;
    const int l16  = lane & 15;
    const int wm   = (w >> 1) * 64;
    const int wn   = (w & 1) * 64;

    f32x4 acc[4][4];
#pragma unroll
    for (int i = 0; i < 4; i++)
#pragma unroll
        for (int j = 0; j < 4; j++) acc[i][j] = (f32x4)0.f;

#pragma unroll 1
    for (int kt = 0; kt < KDIM; kt += 32) {
        __syncthreads();
#pragma unroll
        for (int i = 0; i < 2; i++) {
            int u = tid + i * 256;              // 16B chunk id, 512/plane
            int r = u >> 2, c = u & 3;
            int q = c ^ ((r >> 1) & 3);
            gload16(hsp + (size_t)(mbase + r) * KDIM + kt + q * 8, &Ah[u * 8]);
            gload16(Wp  + (size_t)(nbase + r) * KDIM + kt + q * 8, &Bh[u * 8]);
        }
        __syncthreads();

        f16x8 af[4], bfr[4];
#pragma unroll
        for (int i = 0; i < 4; i++) {
            int r = wm + i * 16 + l16;
            af[i] = *(const f16x8*)&Ah[(r * 4 + (quad ^ ((r >> 1) & 3))) * 8];
        }
#pragma unroll
        for (int j = 0; j < 4; j++) {
            int r = wn + j * 16 + l16;
            bfr[j] = *(const f16x8*)&Bh[(r * 4 + (quad ^ ((r >> 1) & 3))) * 8];
        }
#pragma unroll
        for (int i = 0; i < 4; i++)
#pragma unroll
            for (int j = 0; j < 4; j++)
                acc[i][j] = __builtin_amdgcn_mfma_f32_16x16x32_f16(af[i], bfr[j], acc[i][j], 0, 0, 0);
    }

    if (widx == 2) {
        // V: write transposed [B,H,D,T], 4 consecutive t per ushort4
        unsigned short* vtp = qkvb + 2 * (size_t)NQKV;
#pragma unroll
        for (int j = 0; j < 4; j++) {
            int n = nbase + wn + j * 16 + l16;
            int h = n >> 6, d = n & 63;
            float bj = bias[n];
#pragma unroll
            for (int i = 0; i < 4; i++) {
                int m = mbase + wm + i * 16 + quad * 4;
                int b = m >> 10, t0 = m & 1023;
                ushort4 pk;
                pk.x = f2h(acc[i][j][0] + bj);
                pk.y = f2h(acc[i][j][1] + bj);
                pk.z = f2h(acc[i][j][2] + bj);
                pk.w = f2h(acc[i][j][3] + bj);
                *(ushort4*)(vtp + ((size_t)(b * HH + h) * DD + d) * TT + t0) = pk;
            }
        }
    } else {
        unsigned short* dst = qkvb + (size_t)widx * NQKV;
#pragma unroll
        for (int j = 0; j < 4; j++) {
            int n = nbase + wn + j * 16 + l16;
            int h = n >> 6, d = n & 63;
            float bj = bias[n];
#pragma unroll
            for (int i = 0; i < 4; i++)
#pragma unroll
                for (int rr = 0; rr < 4; rr++) {
                    int m = mbase + wm + i * 16 + quad * 4 + rr;
                    int b = m >> 10, t = m & 1023;
                    dst[(((size_t)(b * HH + h) * TT + t) * DD + d)] =
                        f2h((acc[i][j][rr] + bj) * scale);
                }
        }
    }
}

// ---------------------------------------------------------------------------
// Out projection, 2-term fp16 (unchanged).
// ---------------------------------------------------------------------------
__global__ __launch_bounds__(256)
void outproj_kernel(const unsigned short* __restrict__ ctxh,
                    const unsigned short* __restrict__ ctxl,
                    const unsigned short* __restrict__ wop,
                    const float* __restrict__ bo, float* __restrict__ out)
{
    __shared__ unsigned short Ach[64 * 32], Acl[64 * 32], Bh[128 * 32];

    const int nbase = blockIdx.x * 128;
    const int mbase = blockIdx.y * 64;

    const int tid  = threadIdx.x;
    const int w    = tid >> 6;
    const int lane = tid & 63;
    const int quad = lane >> 4;
    const int l16  = lane & 15;
    const int wm   = (w >> 1) * 32;
    const int wn   = (w & 1) * 64;

    f32x4 acc[2][4];
#pragma unroll
    for (int i = 0; i < 2; i++)
#pragma unroll
        for (int j = 0; j < 4; j++) acc[i][j] = (f32x4)0.f;

#pragma unroll 1
    for (int kt = 0; kt < KDIM; kt += 32) {
        __syncthreads();
        {
            int r = tid >> 2, c = tid & 3;
            int q = c ^ ((r >> 1) & 3);
            size_t ga = (size_t)(mbase + r) * KDIM + kt + q * 8;
            gload16(ctxh + ga, &Ach[tid * 8]);
            gload16(ctxl + ga, &Acl[tid * 8]);
        }
#pragma unroll
        for (int i = 0; i < 2; i++) {
            int u = tid + i * 256;
            int r = u >> 2, c = u & 3;
            int q = c ^ ((r >> 1) & 3);
            gload16(wop + (size_t)(nbase + r) * KDIM + kt + q * 8, &Bh[u * 8]);
        }
        __syncthreads();

        f16x8 ah[2], al[2], bfr[4];
#pragma unroll
        for (int i = 0; i < 2; i++) {
            int r = wm + i * 16 + l16;
            int slot = (r * 4 + (quad ^ ((r >> 1) & 3))) * 8;
            ah[i] = *(const f16x8*)&Ach[slot];
            al[i] = *(const f16x8*)&Acl[slot];
        }
#pragma unroll
        for (int j = 0; j < 4; j++) {
            int r = wn + j * 16 + l16;
            bfr[j] = *(const f16x8*)&Bh[(r * 4 + (quad ^ ((r >> 1) & 3))) * 8];
        }
#pragma unroll
        for (int i = 0; i < 2; i++)
#pragma unroll
            for (int j = 0; j < 4; j++) {
                acc[i][j] = __builtin_amdgcn_mfma_f32_16x16x32_f16(ah[i], bfr[j], acc[i][j], 0, 0, 0);
                acc[i][j] = __builtin_amdgcn_mfma_f32_16x16x32_f16(al[i], bfr[j], acc[i][j], 0, 0, 0);
            }
    }

#pragma unroll
    for (int j = 0; j < 4; j++) {
        int n = nbase + wn + j * 16 + l16;
        float bj = bo[n];
#pragma unroll
        for (int i = 0; i < 2; i++)
#pragma unroll
            for (int rr = 0; rr < 4; rr++) {
                int m = mbase + wm + i * 16 + quad * 4 + rr;
                out[(size_t)m * EE + n] = acc[i][j][rr] + bj;
            }
    }
}

// ---------------------------------------------------------------------------
// MFMA flash attention, fp16. BM=32, 128 threads (2 waves), single-buffer.
// grid (64 bh, 32 mtiles): all m-tiles of one bh share an XCD (id%8=bh%8)
// for K/V L2 locality. LDS = Ks 8K + Vt 8K + Ps 4K = 20 KB -> 8 blocks/CU,
// 16 waves/CU; barriers idle only 2 waves at a time.
// Softmax: per-quad shared max (4 shuffles), row-sums via ones-MFMA
// (lacc = mfma(pf, 1, alpha*lacc)) — no sum shuffle tree.
// ---------------------------------------------------------------------------
__global__ __launch_bounds__(128)
void attn_kernel(const unsigned short* __restrict__ qp_, const unsigned short* __restrict__ kp_,
                 const unsigned short* __restrict__ vtp_,
                 const unsigned short* __restrict__ maskh,
                 unsigned short* __restrict__ ctxh, unsigned short* __restrict__ ctxl)
{
    __shared__ unsigned short Ks[64 * 64];   // rows kv, chunk-swizzled
    __shared__ unsigned short Vt[64 * 64];   // rows d, cols kv, chunk-swizzled
    __shared__ unsigned short Ps[32 * 64];   // XOR-swizzled

    const int bh = blockIdx.x;
    const int b  = bh >> 4;
    const int h  = bh & 15;
    const int m0 = blockIdx.y * 32;
    const size_t hoff = (size_t)bh * TT * DD;
    const unsigned short* qhp = qp_ + hoff;
    const unsigned short* khp = kp_ + hoff;
    const unsigned short* vtp = vtp_ + hoff;   // [D][T] for this bh
    const _Float16* mb = (const _Float16*)(maskh + (size_t)b * TT * TT);

    const int tid  = threadIdx.x;
    const int w    = tid >> 6;      // wave 0..1
    const int lane = tid & 63;
    const int quad = lane >> 4;
    const int l16  = lane & 15;

    // ones B-operand for row-sum MFMA
    f16x8 ones;
#pragma unroll
    for (int j = 0; j < 8; j++) ones[j] = (_Float16)1.0f;

    // Q fragments, resident whole kernel (A-frag: m=l16, k=s*32+quad*8+j)
    f16x8 qf[2];
#pragma unroll
    for (int s = 0; s < 2; s++)
        qf[s] = *(const f16x8*)(qhp + (size_t)(m0 + w * 16 + l16) * DD + s * 32 + quad * 8);

    f32x4 o[4], lacc = (f32x4)0.f;
    float m_q = -INFINITY;          // shared max for this lane's quad (4 rows)
#pragma unroll
    for (int t = 0; t < 4; t++) o[t] = (f32x4)0.f;

#pragma unroll 1
    for (int n0 = 0; n0 < TT; n0 += 64) {
        // mask loads (fp16), issued before barriers to overlap
        _Float16 mreg[4][4];
#pragma unroll
        for (int t = 0; t < 4; t++)
#pragma unroll
            for (int r = 0; r < 4; r++)
                mreg[t][r] = mb[(size_t)(m0 + w * 16 + quad * 4 + r) * TT + n0 + 16 * t + l16];

        __syncthreads();   // previous iteration's readers done with Ks/Vt
#pragma unroll
        for (int i = 0; i < 4; i++) {
            int u = tid + i * 128;
            int r = u >> 3, cp = u & 7;
            int c = cp ^ (r & 7);
            gload16(khp + (size_t)(n0 + r) * DD + c * 8, &Ks[u * 8]);
            gload16(vtp + (size_t)r * TT + n0 + c * 8,   &Vt[u * 8]);
        }
        __syncthreads();

        // S = Q.K^T + mask
        f32x4 st[4];
#pragma unroll
        for (int t = 0; t < 4; t++) st[t] = (f32x4)0.f;
#pragma unroll
        for (int s = 0; s < 2; s++)
#pragma unroll
            for (int t = 0; t < 4; t++) {
                int R = 16 * t + l16;
                const f16x8 kf = *(const f16x8*)&Ks[(R * 8 + ((s * 4 + quad) ^ (R & 7))) * 8];
                st[t] = __builtin_amdgcn_mfma_f32_16x16x32_f16(qf[s], kf, st[t], 0, 0, 0);
            }
#pragma unroll
        for (int t = 0; t < 4; t++)
#pragma unroll
            for (int r = 0; r < 4; r++)
                st[t][r] += (float)mreg[t][r];

        // per-quad shared max: local 16-way max, 4 shuffles (within l16 group)
        float rm = st[0][0];
#pragma unroll
        for (int t = 0; t < 4; t++)
#pragma unroll
            for (int r = 0; r < 4; r++) rm = fmaxf(rm, st[t][r]);
#pragma unroll
        for (int mky = 1; mky < 16; mky <<= 1)
            rm = fmaxf(rm, __shfl_xor(rm, mky));
        float mnew  = fmaxf(m_q, rm);
        float alpha = __expf(m_q - mnew);   // 0 on first iteration
        m_q = mnew;

        // exponentiate, rescale running state
#pragma unroll
        for (int t = 0; t < 4; t++)
#pragma unroll
            for (int r = 0; r < 4; r++)
                st[t][r] = __expf(st[t][r] - m_q);
#pragma unroll
        for (int t = 0; t < 4; t++)
#pragma unroll
            for (int r = 0; r < 4; r++)
                o[t][r] *= alpha;
        lacc *= alpha;

        // P (C-layout) -> fp16 LDS, XOR-swizzled; same-wave RAW via lgkmcnt
#pragma unroll
        for (int t = 0; t < 4; t++)
#pragma unroll
            for (int r = 0; r < 4; r++) {
                int R = w * 16 + quad * 4 + r;
                int j = 16 * t + l16;
                Ps[R * 64 + (((j >> 3) ^ (R & 7)) * 8) + (j & 7)] = f2h(st[t][r]);
            }

        // O += P.V ; lacc += P.1 (row sums)
#pragma unroll
        for (int s = 0; s < 2; s++) {
            int Rr = w * 16 + l16;
            const f16x8 pf = *(const f16x8*)&Ps[Rr * 64 + (((s * 4 + quad) ^ (Rr & 7)) * 8)];
            lacc = __builtin_amdgcn_mfma_f32_16x16x32_f16(pf, ones, lacc, 0, 0, 0);
#pragma unroll
            for (int t = 0; t < 4; t++) {
                int R = 16 * t + l16;
                const f16x8 vf = *(const f16x8*)&Vt[(R * 8 + ((s * 4 + quad) ^ (R & 7))) * 8];
                o[t] = __builtin_amdgcn_mfma_f32_16x16x32_f16(pf, vf, o[t], 0, 0, 0);
            }
        }
    }

    // epilogue: normalize, split fp16 hi/lo ctx planes [B,T,E]
#pragma unroll
    for (int r = 0; r < 4; r++) {
        float inv = 1.0f / lacc[r];
        int m = m0 + w * 16 + quad * 4 + r;
#pragma unroll
        for (int t = 0; t < 4; t++) {
            float val = o[t][r] * inv;
            unsigned short hi, lo;
            split_h(val, hi, lo);
            size_t off = (size_t)(b * TT + m) * EE + h * DD + 16 * t + l16;
            ctxh[off] = hi;
            ctxl[off] = lo;
        }
    }
}

// ---------------------------------------------------------------------------
extern "C" void kernel_launch(void* const* d_in, const int* in_sizes, int n_in,
                              void* d_out, int out_size, void* d_ws, size_t ws_size,
                              hipStream_t stream)
{
    const float* hs   = (const float*)d_in[0];
    const float* mask = (const float*)d_in[1];
    const float* Wq   = (const float*)d_in[2];
    const float* bq   = (const float*)d_in[3];
    const float* Wk   = (const float*)d_in[4];
    const float* bk   = (const float*)d_in[5];
    const float* Wv   = (const float*)d_in[6];
    const float* bv   = (const float*)d_in[7];
    const float* Wo   = (const float*)d_in[8];
    const float* bo   = (const float*)d_in[9];
    float* out = (float*)d_out;

    unsigned short* ws    = (unsigned short*)d_ws;
    unsigned short* hsp   = ws;                                 // fp16 hs (-> ctx_hi)
    unsigned short* wqp   = ws + (size_t)N_HS;                  // wq,wk,wv,wo
    unsigned short* wop   = wqp + 3 * (size_t)N_W;
    unsigned short* qkvb  = wqp + 4 * (size_t)N_W;              // q, k, vT
    unsigned short* qp    = qkvb;
    unsigned short* kp    = qp + (size_t)NQKV;
    unsigned short* vtp   = kp + (size_t)NQKV;                  // V^T [B,H,D,T]
    unsigned short* ctxl  = vtp + (size_t)NQKV;
    unsigned short* maskh = ctxl + (size_t)N_HS;
    unsigned short* ctxh  = ws;                                 // alias hs (dead after qkv)

    split_kernel<<<12288, 256, 0, stream>>>(hs, Wq, Wk, Wv, Wo, mask, ws, maskh);
    qkv_kernel<<<dim3(24, 32), 256, 0, stream>>>(hsp, wqp, bq, bk, bv, qkvb);
    attn_kernel<<<dim3(BB * HH, TT / 32), 128, 0, stream>>>(qp, kp, vtp, maskh, ctxh, ctxl);
    outproj_kernel<<<dim3(8, 64), 256, 0, stream>>>(ctxh, ctxl, wop, bo, out);
}

// Round 8
// 235.577 us; speedup vs baseline: 1.0736x; 1.0370x over previous
//
#include <hip/hip_runtime.h>
#include <math.h>

// Problem constants
#define BB 4
#define TT 1024
#define EE 1024
#define HH 16
#define DD 64
#define KDIM 1024
#define N_HS (4096 * 1024)     // hidden_states elems (also ctx)
#define N_W  (1024 * 1024)     // one weight matrix elems
#define NQKV (BB * HH * TT * DD)
#define NMASK (BB * TT * TT)

typedef _Float16 f16x8 __attribute__((ext_vector_type(8)));   // 4 VGPRs
typedef _Float16 f16x4 __attribute__((ext_vector_type(4)));   // 2 VGPRs
typedef float    f32x4 __attribute__((ext_vector_type(4)));

// fp32 -> fp16 bits, RTNE
__device__ __forceinline__ unsigned short f2h(float x) {
    _Float16 h = (_Float16)x;
    return __builtin_bit_cast(unsigned short, h);
}
// split x = hi + lo, both fp16
__device__ __forceinline__ void split_h(float x, unsigned short& hi, unsigned short& lo) {
    _Float16 h = (_Float16)x;
    hi = __builtin_bit_cast(unsigned short, h);
    lo = f2h(x - (float)h);
}

// async global->LDS 16B copy
__device__ __forceinline__ void gload16(const void* g, void* l) {
    __builtin_amdgcn_global_load_lds(
        (const __attribute__((address_space(1))) void*)g,
        (__attribute__((address_space(3))) void*)l, 16, 0, 0);
}

// ---------------------------------------------------------------------------
// Elementwise fp32 -> fp16 convert: hs + 4 weights + mask.
// ws layout (ushort units):
//   [0]                hs (N_HS)               (aliased as ctx_hi later)
//   [N_HS]             wq, wk, wv, wo          (N_W each)
//   [N_HS+4N_W]        q, k, v                 (NQKV each)
//   [.. +3NQKV]        vT (NQKV, [B,H,D,T])
//   [.. +NQKV]         ctx_lo                  (N_HS)
//   [.. +N_HS]         mask fp16               (NMASK)
// ---------------------------------------------------------------------------
__global__ __launch_bounds__(256)
void split_kernel(const float* __restrict__ hs,
                  const float* __restrict__ Wq, const float* __restrict__ Wk,
                  const float* __restrict__ Wv, const float* __restrict__ Wo,
                  const float* __restrict__ maskp,
                  unsigned short* __restrict__ ws,
                  unsigned short* __restrict__ maskh)
{
    const int u = blockIdx.x * 256 + threadIdx.x;   // float4 id, 3,145,728 total
    const float* src;
    unsigned short* dst;
    if (u < (N_HS / 4)) {
        src = hs + (size_t)u * 4;
        dst = ws + (size_t)u * 4;
    } else if (u < (N_HS / 4) + N_W) {              // 4 weights = 4*(N_W/4) float4
        int v = u - N_HS / 4;
        int wsel = v >> 18;             // N_W/4 = 262144 float4 per weight
        int wo   = v & 0x3FFFF;
        const float* Wsrc = (wsel == 0) ? Wq : (wsel == 1) ? Wk : (wsel == 2) ? Wv : Wo;
        src = Wsrc + (size_t)wo * 4;
        dst = ws + (size_t)N_HS + (size_t)wsel * N_W + (size_t)wo * 4;
    } else {
        int v = u - (N_HS / 4) - N_W;
        src = maskp + (size_t)v * 4;
        dst = maskh + (size_t)v * 4;
    }
    float4 x = *(const float4*)src;
    ushort4 h4;
    h4.x = f2h(x.x); h4.y = f2h(x.y); h4.z = f2h(x.z); h4.w = f2h(x.w);
    *(ushort4*)dst = h4;
}

// ---------------------------------------------------------------------------
// QKV projection, single-fp16 MFMA; q/k/v all scattered to [B,H,T,D]
// (coalesced 2B-per-lane segments; the V transpose is a separate kernel).
// ---------------------------------------------------------------------------
__global__ __launch_bounds__(256)
void qkv_kernel(const unsigned short* __restrict__ hsp,
                const unsigned short* __restrict__ wqp,
                const float* __restrict__ bq, const float* __restrict__ bk,
                const float* __restrict__ bv,
                unsigned short* __restrict__ qkvb)
{
    __shared__ unsigned short Ah[128 * 32], Bh[128 * 32];

    const int widx  = blockIdx.x >> 3;
    const int nbase = (blockIdx.x & 7) * 128;
    const int mbase = blockIdx.y * 128;
    const unsigned short* Wp = wqp + (size_t)widx * N_W;
    const float* bias = (widx == 0) ? bq : (widx == 1) ? bk : bv;
    unsigned short* dst = qkvb + (size_t)widx * NQKV;
    const float scale = (widx == 0) ? 0.125f : 1.0f;   // D^-0.5

    const int tid  = threadIdx.x;
    const int w    = tid >> 6;
    const int lane = tid & 63;
    const int quad = lane >> 4;
    const int l16  = lane & 15;
    const int wm   = (w >> 1) * 64;
    const int wn   = (w & 1) * 64;

    f32x4 acc[4][4];
#pragma unroll
    for (int i = 0; i < 4; i++)
#pragma unroll
        for (int j = 0; j < 4; j++) acc[i][j] = (f32x4)0.f;

#pragma unroll 1
    for (int kt = 0; kt < KDIM; kt += 32) {
        __syncthreads();
#pragma unroll
        for (int i = 0; i < 2; i++) {
            int u = tid + i * 256;              // 16B chunk id, 512/plane
            int r = u >> 2, c = u & 3;
            int q = c ^ ((r >> 1) & 3);
            gload16(hsp + (size_t)(mbase + r) * KDIM + kt + q * 8, &Ah[u * 8]);
            gload16(Wp  + (size_t)(nbase + r) * KDIM + kt + q * 8, &Bh[u * 8]);
        }
        __syncthreads();

        f16x8 af[4], bfr[4];
#pragma unroll
        for (int i = 0; i < 4; i++) {
            int r = wm + i * 16 + l16;
            af[i] = *(const f16x8*)&Ah[(r * 4 + (quad ^ ((r >> 1) & 3))) * 8];
        }
#pragma unroll
        for (int j = 0; j < 4; j++) {
            int r = wn + j * 16 + l16;
            bfr[j] = *(const f16x8*)&Bh[(r * 4 + (quad ^ ((r >> 1) & 3))) * 8];
        }
#pragma unroll
        for (int i = 0; i < 4; i++)
#pragma unroll
            for (int j = 0; j < 4; j++)
                acc[i][j] = __builtin_amdgcn_mfma_f32_16x16x32_f16(af[i], bfr[j], acc[i][j], 0, 0, 0);
    }

    // epilogue: +bias, *scale, fp16, scatter to [B,H,T,D]
#pragma unroll
    for (int j = 0; j < 4; j++) {
        int n = nbase + wn + j * 16 + l16;
        int h = n >> 6, d = n & 63;
        float bj = bias[n];
#pragma unroll
        for (int i = 0; i < 4; i++)
#pragma unroll
            for (int rr = 0; rr < 4; rr++) {
                int m = mbase + wm + i * 16 + quad * 4 + rr;
                int b = m >> 10, t = m & 1023;
                dst[(((size_t)(b * HH + h) * TT + t) * DD + d)] =
                    f2h((acc[i][j][rr] + bj) * scale);
            }
    }
}

// ---------------------------------------------------------------------------
// V transpose: [B,H,T,D] -> [B,H,D,T] fp16, via LDS tile (coalesced both ways).
// ---------------------------------------------------------------------------
__global__ __launch_bounds__(256)
void vtrans_kernel(const unsigned short* __restrict__ vp,
                   unsigned short* __restrict__ vtp)
{
    __shared__ unsigned short Ts[64 * 72];
    const int bh = blockIdx.y;
    const int t0 = blockIdx.x * 64;
    const unsigned short* src = vp  + (size_t)bh * TT * DD + (size_t)t0 * DD;
    unsigned short*       dst = vtp + (size_t)bh * DD * TT + t0;
    const int tid = threadIdx.x;

#pragma unroll
    for (int i = 0; i < 2; i++) {
        int id = tid + i * 256;           // 512 uint4: row r (token), chunk c (8 d)
        int r = id >> 3, c = id & 7;
        *(uint4*)&Ts[r * 72 + c * 8] = *(const uint4*)(src + (size_t)r * DD + c * 8);
    }
    __syncthreads();
#pragma unroll
    for (int i = 0; i < 2; i++) {
        int id = tid + i * 256;           // 512 uint4: row d, chunk c (8 tokens)
        int d = id >> 3, c = id & 7;
        unsigned short tmp[8];
#pragma unroll
        for (int j = 0; j < 8; j++) tmp[j] = Ts[(c * 8 + j) * 72 + d];
        uint4 o;
        o.x = (unsigned int)tmp[0] | ((unsigned int)tmp[1] << 16);
        o.y = (unsigned int)tmp[2] | ((unsigned int)tmp[3] << 16);
        o.z = (unsigned int)tmp[4] | ((unsigned int)tmp[5] << 16);
        o.w = (unsigned int)tmp[6] | ((unsigned int)tmp[7] << 16);
        *(uint4*)(dst + (size_t)d * TT + c * 8) = o;
    }
}

// ---------------------------------------------------------------------------
// Out projection, 2-term fp16 (unchanged).
// ---------------------------------------------------------------------------
__global__ __launch_bounds__(256)
void outproj_kernel(const unsigned short* __restrict__ ctxh,
                    const unsigned short* __restrict__ ctxl,
                    const unsigned short* __restrict__ wop,
                    const float* __restrict__ bo, float* __restrict__ out)
{
    __shared__ unsigned short Ach[64 * 32], Acl[64 * 32], Bh[128 * 32];

    const int nbase = blockIdx.x * 128;
    const int mbase = blockIdx.y * 64;

    const int tid  = threadIdx.x;
    const int w    = tid >> 6;
    const int lane = tid & 63;
    const int quad = lane >> 4;
    const int l16  = lane & 15;
    const int wm   = (w >> 1) * 32;
    const int wn   = (w & 1) * 64;

    f32x4 acc[2][4];
#pragma unroll
    for (int i = 0; i < 2; i++)
#pragma unroll
        for (int j = 0; j < 4; j++) acc[i][j] = (f32x4)0.f;

#pragma unroll 1
    for (int kt = 0; kt < KDIM; kt += 32) {
        __syncthreads();
        {
            int r = tid >> 2, c = tid & 3;
            int q = c ^ ((r >> 1) & 3);
            size_t ga = (size_t)(mbase + r) * KDIM + kt + q * 8;
            gload16(ctxh + ga, &Ach[tid * 8]);
            gload16(ctxl + ga, &Acl[tid * 8]);
        }
#pragma unroll
        for (int i = 0; i < 2; i++) {
            int u = tid + i * 256;
            int r = u >> 2, c = u & 3;
            int q = c ^ ((r >> 1) & 3);
            gload16(wop + (size_t)(nbase + r) * KDIM + kt + q * 8, &Bh[u * 8]);
        }
        __syncthreads();

        f16x8 ah[2], al[2], bfr[4];
#pragma unroll
        for (int i = 0; i < 2; i++) {
            int r = wm + i * 16 + l16;
            int slot = (r * 4 + (quad ^ ((r >> 1) & 3))) * 8;
            ah[i] = *(const f16x8*)&Ach[slot];
            al[i] = *(const f16x8*)&Acl[slot];
        }
#pragma unroll
        for (int j = 0; j < 4; j++) {
            int r = wn + j * 16 + l16;
            bfr[j] = *(const f16x8*)&Bh[(r * 4 + (quad ^ ((r >> 1) & 3))) * 8];
        }
#pragma unroll
        for (int i = 0; i < 2; i++)
#pragma unroll
            for (int j = 0; j < 4; j++) {
                acc[i][j] = __builtin_amdgcn_mfma_f32_16x16x32_f16(ah[i], bfr[j], acc[i][j], 0, 0, 0);
                acc[i][j] = __builtin_amdgcn_mfma_f32_16x16x32_f16(al[i], bfr[j], acc[i][j], 0, 0, 0);
            }
    }

#pragma unroll
    for (int j = 0; j < 4; j++) {
        int n = nbase + wn + j * 16 + l16;
        float bj = bo[n];
#pragma unroll
        for (int i = 0; i < 2; i++)
#pragma unroll
            for (int rr = 0; rr < 4; rr++) {
                int m = mbase + wm + i * 16 + quad * 4 + rr;
                out[(size_t)m * EE + n] = acc[i][j][rr] + bj;
            }
    }
}

// ---------------------------------------------------------------------------
// MFMA flash attention, S^T formulation. BM=32 (16 q-rows/wave), BN=64.
// S^T = K.Q^T via mfma(A=K-frag, B=Q-frag): C cols = m (lane), rows = kv.
// Softmax per-lane: 15 local VALU + 2 shuffles (exact row max); P^T stays in
// registers (cvt to f16x4) and feeds mfma_16x16x16f16 as B directly; V^T
// frags are A (ds_read_b64 from swizzled Vt). l = local sums + 2 epilogue
// shuffles. Mask tile staged coalesced into padded LDS. Epilogue transposes
// O^T through LDS once for coalesced ctx writes.
// LDS = Ks 8K + Vt 8K + Ms 4.5K = 20.5 KB -> 7 blocks/CU.
// ---------------------------------------------------------------------------
__global__ __launch_bounds__(128)
void attn_kernel(const unsigned short* __restrict__ qp_, const unsigned short* __restrict__ kp_,
                 const unsigned short* __restrict__ vtp_,
                 const unsigned short* __restrict__ maskh,
                 unsigned short* __restrict__ ctxh, unsigned short* __restrict__ ctxl)
{
    __shared__ unsigned short Ks[64 * 64];   // [kv][d], chunk-swizzled
    __shared__ unsigned short Vt[64 * 64];   // [d][kv], chunk-swizzled
    __shared__ unsigned short Ms[32 * 72];   // mask [m][kv], padded

    const int bh = blockIdx.x;
    const int b  = bh >> 4;
    const int h  = bh & 15;
    const int m0 = blockIdx.y * 32;
    const size_t hoff = (size_t)bh * TT * DD;
    const unsigned short* qhp = qp_ + hoff;
    const unsigned short* khp = kp_ + hoff;
    const unsigned short* vtp = vtp_ + hoff;   // [D][T] for this bh
    const unsigned short* mb  = maskh + (size_t)b * TT * TT;

    const int tid  = threadIdx.x;
    const int w    = tid >> 6;      // wave 0..1
    const int lane = tid & 63;
    const int quad = lane >> 4;
    const int l16  = lane & 15;

    // Q fragment (B-operand of S^T mfma): lane n=l16 <-> m = m0+w*16+l16,
    // k = s*32 + quad*8 + j  — same data layout as the old A-frag.
    f16x8 qf[2];
#pragma unroll
    for (int s = 0; s < 2; s++)
        qf[s] = *(const f16x8*)(qhp + (size_t)(m0 + w * 16 + l16) * DD + s * 32 + quad * 8);

    // O^T accumulators: o[u] rows d=16u+quad*4+r, col m=l16
    f32x4 o[4];
#pragma unroll
    for (int u = 0; u < 4; u++) o[u] = (f32x4)0.f;
    float m_run = -INFINITY, lacc = 0.f;

#pragma unroll 1
    for (int n0 = 0; n0 < TT; n0 += 64) {
        __syncthreads();   // prev-iter readers done with Ks/Vt/Ms
        // K [kv][d] and V^T [d][kv] via async DMA, source-side chunk swizzle
#pragma unroll
        for (int i = 0; i < 4; i++) {
            int u = tid + i * 128;
            int r = u >> 3, cp = u & 7;
            int c = cp ^ (r & 7);
            gload16(khp + (size_t)(n0 + r) * DD + c * 8, &Ks[u * 8]);
            gload16(vtp + (size_t)r * TT + n0 + c * 8,   &Vt[u * 8]);
        }
        // mask tile [32 m][64 kv] -> padded LDS (coalesced global read)
#pragma unroll
        for (int i = 0; i < 2; i++) {
            int cch = tid * 2 + i;            // 256 16B chunks
            int row = cch >> 3, c8 = cch & 7;
            uint4 mv = *(const uint4*)(mb + (size_t)(m0 + row) * TT + n0 + c8 * 8);
            *(uint4*)&Ms[row * 72 + c8 * 8] = mv;
        }
        __syncthreads();

        // S^T = K.Q^T : st[t] rows kv=16t+quad*4+r, col m=l16
        f32x4 st[4];
#pragma unroll
        for (int t = 0; t < 4; t++) st[t] = (f32x4)0.f;
#pragma unroll
        for (int s = 0; s < 2; s++)
#pragma unroll
            for (int t = 0; t < 4; t++) {
                int R = 16 * t + l16;
                const f16x8 kf = *(const f16x8*)&Ks[(R * 8 + ((s * 4 + quad) ^ (R & 7))) * 8];
                st[t] = __builtin_amdgcn_mfma_f32_16x16x32_f16(kf, qf[s], st[t], 0, 0, 0);
            }
        // + mask (row m = w*16+l16, cols 16t+quad*4+r)
#pragma unroll
        for (int t = 0; t < 4; t++) {
            f16x4 mk = *(const f16x4*)&Ms[(w * 16 + l16) * 72 + 16 * t + quad * 4];
#pragma unroll
            for (int r = 0; r < 4; r++)
                st[t][r] += (float)mk[r];
        }

        // softmax: all 16 values in this lane share row m -> local max + 2 shuffles
        float rm = st[0][0];
#pragma unroll
        for (int t = 0; t < 4; t++)
#pragma unroll
            for (int r = 0; r < 4; r++) rm = fmaxf(rm, st[t][r]);
        rm = fmaxf(rm, __shfl_xor(rm, 16));
        rm = fmaxf(rm, __shfl_xor(rm, 32));
        float mnew  = fmaxf(m_run, rm);
        float alpha = __expf(m_run - mnew);   // 0 on first iteration
        m_run = mnew;

        float ls = 0.f;
#pragma unroll
        for (int t = 0; t < 4; t++)
#pragma unroll
            for (int r = 0; r < 4; r++) {
                float p = __expf(st[t][r] - m_run);
                st[t][r] = p;
                ls += p;
            }
        lacc = lacc * alpha + ls;             // per-quad partial; finished in epilogue
#pragma unroll
        for (int u = 0; u < 4; u++)
#pragma unroll
            for (int r = 0; r < 4; r++)
                o[u][r] *= alpha;

        // P^T fragments (B-operand of 16x16x16): pf[t][j] = P^T[16t+quad*4+j][l16]
        f16x4 pf[4];
#pragma unroll
        for (int t = 0; t < 4; t++)
#pragma unroll
            for (int r = 0; r < 4; r++)
                pf[t][r] = (_Float16)st[t][r];

        // O^T += V^T . P^T  (A = V^T frag, 4 d-tiles x 4 kv-tiles)
#pragma unroll
        for (int t = 0; t < 4; t++)
#pragma unroll
            for (int u = 0; u < 4; u++) {
                int r_ = 16 * u + l16;
                int lc = 2 * t + (quad >> 1);              // logical 16B chunk
                int pc = lc ^ (r_ & 7);
                const f16x4 vf = *(const f16x4*)&Vt[r_ * 64 + pc * 8 + (quad & 1) * 4];
                o[u] = __builtin_amdgcn_mfma_f32_16x16x16f16(vf, pf[t], o[u], 0, 0, 0);
            }
    }

    // finish row sums across quads (each quad held a disjoint kv subset)
    lacc += __shfl_xor(lacc, 16);
    lacc += __shfl_xor(lacc, 32);
    const float inv = 1.0f / lacc;

    // epilogue: transpose O^T through LDS (reuse Ks=hi, Vt=lo; stride 72)
    __syncthreads();   // last-iter Ks/Vt readers done
#pragma unroll
    for (int u = 0; u < 4; u++)
#pragma unroll
        for (int r = 0; r < 4; r++) {
            float val = o[u][r] * inv;
            unsigned short hi, lo;
            split_h(val, hi, lo);
            int mloc = w * 16 + l16;
            int d    = 16 * u + quad * 4 + r;
            Ks[mloc * 72 + d] = hi;
            Vt[mloc * 72 + d] = lo;
        }
    __syncthreads();
    {
        int row = tid >> 2;            // 0..31
        int c16 = (tid & 3) * 16;      // 16 d per thread
        size_t base = ((size_t)(b * TT + m0 + row)) * EE + h * DD + c16;
        uint4 h0 = *(const uint4*)&Ks[row * 72 + c16];
        uint4 h1 = *(const uint4*)&Ks[row * 72 + c16 + 8];
        *(uint4*)(ctxh + base)     = h0;
        *(uint4*)(ctxh + base + 8) = h1;
        uint4 l0 = *(const uint4*)&Vt[row * 72 + c16];
        uint4 l1 = *(const uint4*)&Vt[row * 72 + c16 + 8];
        *(uint4*)(ctxl + base)     = l0;
        *(uint4*)(ctxl + base + 8) = l1;
    }
}

// ---------------------------------------------------------------------------
extern "C" void kernel_launch(void* const* d_in, const int* in_sizes, int n_in,
                              void* d_out, int out_size, void* d_ws, size_t ws_size,
                              hipStream_t stream)
{
    const float* hs   = (const float*)d_in[0];
    const float* mask = (const float*)d_in[1];
    const float* Wq   = (const float*)d_in[2];
    const float* bq   = (const float*)d_in[3];
    const float* Wk   = (const float*)d_in[4];
    const float* bk   = (const float*)d_in[5];
    const float* Wv   = (const float*)d_in[6];
    const float* bv   = (const float*)d_in[7];
    const float* Wo   = (const float*)d_in[8];
    const float* bo   = (const float*)d_in[9];
    float* out = (float*)d_out;

    unsigned short* ws    = (unsigned short*)d_ws;
    unsigned short* hsp   = ws;                                 // fp16 hs (-> ctx_hi)
    unsigned short* wqp   = ws + (size_t)N_HS;                  // wq,wk,wv,wo
    unsigned short* wop   = wqp + 3 * (size_t)N_W;
    unsigned short* qkvb  = wqp + 4 * (size_t)N_W;              // q, k, v
    unsigned short* qp    = qkvb;
    unsigned short* kp    = qp + (size_t)NQKV;
    unsigned short* vp    = kp + (size_t)NQKV;
    unsigned short* vtp   = vp + (size_t)NQKV;                  // V^T [B,H,D,T]
    unsigned short* ctxl  = vtp + (size_t)NQKV;
    unsigned short* maskh = ctxl + (size_t)N_HS;
    unsigned short* ctxh  = ws;                                 // alias hs (dead after qkv)

    split_kernel<<<12288, 256, 0, stream>>>(hs, Wq, Wk, Wv, Wo, mask, ws, maskh);
    qkv_kernel<<<dim3(24, 32), 256, 0, stream>>>(hsp, wqp, bq, bk, bv, qkvb);
    vtrans_kernel<<<dim3(TT / 64, BB * HH), 256, 0, stream>>>(vp, vtp);
    attn_kernel<<<dim3(BB * HH, TT / 32), 128, 0, stream>>>(qp, kp, vtp, maskh, ctxh, ctxl);
    outproj_kernel<<<dim3(8, 64), 256, 0, stream>>>(ctxh, ctxl, wop, bo, out);
}

// Round 9
// 230.003 us; speedup vs baseline: 1.0996x; 1.0242x over previous
//
#include <hip/hip_runtime.h>
#include <math.h>

// Problem constants
#define BB 4
#define TT 1024
#define EE 1024
#define HH 16
#define DD 64
#define KDIM 1024
#define N_HS (4096 * 1024)     // hidden_states elems (also ctx)
#define N_W  (1024 * 1024)     // one weight matrix elems
#define NQKV (BB * HH * TT * DD)
#define NMASK (BB * TT * TT)

typedef _Float16 f16x8 __attribute__((ext_vector_type(8)));   // 4 VGPRs
typedef _Float16 f16x4 __attribute__((ext_vector_type(4)));   // 2 VGPRs
typedef float    f32x4 __attribute__((ext_vector_type(4)));

// fp32 -> fp16 bits, RTNE
__device__ __forceinline__ unsigned short f2h(float x) {
    _Float16 h = (_Float16)x;
    return __builtin_bit_cast(unsigned short, h);
}

// async global->LDS 16B copy
__device__ __forceinline__ void gload16(const void* g, void* l) {
    __builtin_amdgcn_global_load_lds(
        (const __attribute__((address_space(1))) void*)g,
        (__attribute__((address_space(3))) void*)l, 16, 0, 0);
}

// ---------------------------------------------------------------------------
// Elementwise fp32 -> fp16 convert: hs + 4 weights + mask.
// ws layout (ushort units):
//   [0]                hs (N_HS)               (aliased as ctx_hi later)
//   [N_HS]             wq, wk, wv, wo          (N_W each)
//   [N_HS+4N_W]        q, k, v                 (NQKV each)
//   [.. +3NQKV]        vT (NQKV, [B,H,D,T])
//   [.. +NQKV]         mask fp16               (NMASK)
// ---------------------------------------------------------------------------
__global__ __launch_bounds__(256)
void split_kernel(const float* __restrict__ hs,
                  const float* __restrict__ Wq, const float* __restrict__ Wk,
                  const float* __restrict__ Wv, const float* __restrict__ Wo,
                  const float* __restrict__ maskp,
                  unsigned short* __restrict__ ws,
                  unsigned short* __restrict__ maskh)
{
    const int u = blockIdx.x * 256 + threadIdx.x;   // float4 id, 3,145,728 total
    const float* src;
    unsigned short* dst;
    if (u < (N_HS / 4)) {
        src = hs + (size_t)u * 4;
        dst = ws + (size_t)u * 4;
    } else if (u < (N_HS / 4) + N_W) {              // 4 weights = 4*(N_W/4) float4
        int v = u - N_HS / 4;
        int wsel = v >> 18;             // N_W/4 = 262144 float4 per weight
        int wo   = v & 0x3FFFF;
        const float* Wsrc = (wsel == 0) ? Wq : (wsel == 1) ? Wk : (wsel == 2) ? Wv : Wo;
        src = Wsrc + (size_t)wo * 4;
        dst = ws + (size_t)N_HS + (size_t)wsel * N_W + (size_t)wo * 4;
    } else {
        int v = u - (N_HS / 4) - N_W;
        src = maskp + (size_t)v * 4;
        dst = maskh + (size_t)v * 4;
    }
    float4 x = *(const float4*)src;
    ushort4 h4;
    h4.x = f2h(x.x); h4.y = f2h(x.y); h4.z = f2h(x.z); h4.w = f2h(x.w);
    *(ushort4*)dst = h4;
}

// ---------------------------------------------------------------------------
// QKV projection, single-fp16 MFMA; q/k/v scattered to [B,H,T,D].
// ---------------------------------------------------------------------------
__global__ __launch_bounds__(256)
void qkv_kernel(const unsigned short* __restrict__ hsp,
                const unsigned short* __restrict__ wqp,
                const float* __restrict__ bq, const float* __restrict__ bk,
                const float* __restrict__ bv,
                unsigned short* __restrict__ qkvb)
{
    __shared__ unsigned short Ah[128 * 32], Bh[128 * 32];

    const int widx  = blockIdx.x >> 3;
    const int nbase = (blockIdx.x & 7) * 128;
    const int mbase = blockIdx.y * 128;
    const unsigned short* Wp = wqp + (size_t)widx * N_W;
    const float* bias = (widx == 0) ? bq : (widx == 1) ? bk : bv;
    unsigned short* dst = qkvb + (size_t)widx * NQKV;
    const float scale = (widx == 0) ? 0.125f : 1.0f;   // D^-0.5

    const int tid  = threadIdx.x;
    const int w    = tid >> 6;
    const int lane = tid & 63;
    const int quad = lane >> 4;
    const int l16  = lane & 15;
    const int wm   = (w >> 1) * 64;
    const int wn   = (w & 1) * 64;

    f32x4 acc[4][4];
#pragma unroll
    for (int i = 0; i < 4; i++)
#pragma unroll
        for (int j = 0; j < 4; j++) acc[i][j] = (f32x4)0.f;

#pragma unroll 1
    for (int kt = 0; kt < KDIM; kt += 32) {
        __syncthreads();
#pragma unroll
        for (int i = 0; i < 2; i++) {
            int u = tid + i * 256;              // 16B chunk id, 512/plane
            int r = u >> 2, c = u & 3;
            int q = c ^ ((r >> 1) & 3);
            gload16(hsp + (size_t)(mbase + r) * KDIM + kt + q * 8, &Ah[u * 8]);
            gload16(Wp  + (size_t)(nbase + r) * KDIM + kt + q * 8, &Bh[u * 8]);
        }
        __syncthreads();

        f16x8 af[4], bfr[4];
#pragma unroll
        for (int i = 0; i < 4; i++) {
            int r = wm + i * 16 + l16;
            af[i] = *(const f16x8*)&Ah[(r * 4 + (quad ^ ((r >> 1) & 3))) * 8];
        }
#pragma unroll
        for (int j = 0; j < 4; j++) {
            int r = wn + j * 16 + l16;
            bfr[j] = *(const f16x8*)&Bh[(r * 4 + (quad ^ ((r >> 1) & 3))) * 8];
        }
#pragma unroll
        for (int i = 0; i < 4; i++)
#pragma unroll
            for (int j = 0; j < 4; j++)
                acc[i][j] = __builtin_amdgcn_mfma_f32_16x16x32_f16(af[i], bfr[j], acc[i][j], 0, 0, 0);
    }

    // epilogue: +bias, *scale, fp16, scatter to [B,H,T,D]
#pragma unroll
    for (int j = 0; j < 4; j++) {
        int n = nbase + wn + j * 16 + l16;
        int h = n >> 6, d = n & 63;
        float bj = bias[n];
#pragma unroll
        for (int i = 0; i < 4; i++)
#pragma unroll
            for (int rr = 0; rr < 4; rr++) {
                int m = mbase + wm + i * 16 + quad * 4 + rr;
                int b = m >> 10, t = m & 1023;
                dst[(((size_t)(b * HH + h) * TT + t) * DD + d)] =
                    f2h((acc[i][j][rr] + bj) * scale);
            }
    }
}

// ---------------------------------------------------------------------------
// V transpose: [B,H,T,D] -> [B,H,D,T] fp16, via LDS tile (coalesced both ways).
// ---------------------------------------------------------------------------
__global__ __launch_bounds__(256)
void vtrans_kernel(const unsigned short* __restrict__ vp,
                   unsigned short* __restrict__ vtp)
{
    __shared__ unsigned short Ts[64 * 72];
    const int bh = blockIdx.y;
    const int t0 = blockIdx.x * 64;
    const unsigned short* src = vp  + (size_t)bh * TT * DD + (size_t)t0 * DD;
    unsigned short*       dst = vtp + (size_t)bh * DD * TT + t0;
    const int tid = threadIdx.x;

#pragma unroll
    for (int i = 0; i < 2; i++) {
        int id = tid + i * 256;           // 512 uint4: row r (token), chunk c (8 d)
        int r = id >> 3, c = id & 7;
        *(uint4*)&Ts[r * 72 + c * 8] = *(const uint4*)(src + (size_t)r * DD + c * 8);
    }
    __syncthreads();
#pragma unroll
    for (int i = 0; i < 2; i++) {
        int id = tid + i * 256;           // 512 uint4: row d, chunk c (8 tokens)
        int d = id >> 3, c = id & 7;
        unsigned short tmp[8];
#pragma unroll
        for (int j = 0; j < 8; j++) tmp[j] = Ts[(c * 8 + j) * 72 + d];
        uint4 o;
        o.x = (unsigned int)tmp[0] | ((unsigned int)tmp[1] << 16);
        o.y = (unsigned int)tmp[2] | ((unsigned int)tmp[3] << 16);
        o.z = (unsigned int)tmp[4] | ((unsigned int)tmp[5] << 16);
        o.w = (unsigned int)tmp[6] | ((unsigned int)tmp[7] << 16);
        *(uint4*)(dst + (size_t)d * TT + c * 8) = o;
    }
}

// ---------------------------------------------------------------------------
// Out projection, SINGLE fp16: out = ctx_hi @ Wo^T + bo. Error from dropped
// lo-term ~5e-6 (|ctx|~0.03 damped through Wo dot) — negligible vs 1.46e-3.
// Tile 64m x 128n, BK=32, grid 8x64 = 512 blocks. LDS 12 KB.
// ---------------------------------------------------------------------------
__global__ __launch_bounds__(256)
void outproj_kernel(const unsigned short* __restrict__ ctxh,
                    const unsigned short* __restrict__ wop,
                    const float* __restrict__ bo, float* __restrict__ out)
{
    __shared__ unsigned short Ach[64 * 32], Bh[128 * 32];

    const int nbase = blockIdx.x * 128;
    const int mbase = blockIdx.y * 64;

    const int tid  = threadIdx.x;
    const int w    = tid >> 6;
    const int lane = tid & 63;
    const int quad = lane >> 4;
    const int l16  = lane & 15;
    const int wm   = (w >> 1) * 32;
    const int wn   = (w & 1) * 64;

    f32x4 acc[2][4];
#pragma unroll
    for (int i = 0; i < 2; i++)
#pragma unroll
        for (int j = 0; j < 4; j++) acc[i][j] = (f32x4)0.f;

#pragma unroll 1
    for (int kt = 0; kt < KDIM; kt += 32) {
        __syncthreads();
        {
            int r = tid >> 2, c = tid & 3;
            int q = c ^ ((r >> 1) & 3);
            gload16(ctxh + (size_t)(mbase + r) * KDIM + kt + q * 8, &Ach[tid * 8]);
        }
#pragma unroll
        for (int i = 0; i < 2; i++) {
            int u = tid + i * 256;
            int r = u >> 2, c = u & 3;
            int q = c ^ ((r >> 1) & 3);
            gload16(wop + (size_t)(nbase + r) * KDIM + kt + q * 8, &Bh[u * 8]);
        }
        __syncthreads();

        f16x8 ah[2], bfr[4];
#pragma unroll
        for (int i = 0; i < 2; i++) {
            int r = wm + i * 16 + l16;
            ah[i] = *(const f16x8*)&Ach[(r * 4 + (quad ^ ((r >> 1) & 3))) * 8];
        }
#pragma unroll
        for (int j = 0; j < 4; j++) {
            int r = wn + j * 16 + l16;
            bfr[j] = *(const f16x8*)&Bh[(r * 4 + (quad ^ ((r >> 1) & 3))) * 8];
        }
#pragma unroll
        for (int i = 0; i < 2; i++)
#pragma unroll
            for (int j = 0; j < 4; j++)
                acc[i][j] = __builtin_amdgcn_mfma_f32_16x16x32_f16(ah[i], bfr[j], acc[i][j], 0, 0, 0);
    }

#pragma unroll
    for (int j = 0; j < 4; j++) {
        int n = nbase + wn + j * 16 + l16;
        float bj = bo[n];
#pragma unroll
        for (int i = 0; i < 2; i++)
#pragma unroll
            for (int rr = 0; rr < 4; rr++) {
                int m = mbase + wm + i * 16 + quad * 4 + rr;
                out[(size_t)m * EE + n] = acc[i][j][rr] + bj;
            }
    }
}

// ---------------------------------------------------------------------------
// MFMA flash attention. S^T = K.Q^T (per-lane scalar softmax state, 2-shuffle
// exact max), then P^T -> per-wave Ps[m][kv] strip via 4 b64 writes, PV in
// standard orientation: A = P (b128 from own strip, no barrier), B = V^T
// (b128, R=16v+l16 pattern — measured 0 conflicts in R7). O standard C-layout;
// alpha/inv fetched cross-quad by 4 shuffles. Mask: global b64 register loads.
// LDS = Ks 8K + Vt 8K + Ps 4.5K = 20.6 KB -> 7 blocks/CU.
// ---------------------------------------------------------------------------
__global__ __launch_bounds__(128)
void attn_kernel(const unsigned short* __restrict__ qp_, const unsigned short* __restrict__ kp_,
                 const unsigned short* __restrict__ vtp_,
                 const unsigned short* __restrict__ maskh,
                 unsigned short* __restrict__ ctxh)
{
    __shared__ unsigned short Ks[64 * 64];   // [kv][d], chunk-swizzled
    __shared__ unsigned short Vt[64 * 64];   // [d][kv], chunk-swizzled
    __shared__ unsigned short Ps[32 * 72];   // P[m][kv], per-wave 16-row strips

    const int bh = blockIdx.x;
    const int b  = bh >> 4;
    const int h  = bh & 15;
    const int m0 = blockIdx.y * 32;
    const size_t hoff = (size_t)bh * TT * DD;
    const unsigned short* qhp = qp_ + hoff;
    const unsigned short* khp = kp_ + hoff;
    const unsigned short* vtp = vtp_ + hoff;   // [D][T] for this bh
    const _Float16* mb = (const _Float16*)(maskh + (size_t)b * TT * TT);

    const int tid  = threadIdx.x;
    const int w    = tid >> 6;      // wave 0..1
    const int lane = tid & 63;
    const int quad = lane >> 4;
    const int l16  = lane & 15;
    const int mrow = m0 + w * 16 + l16;      // this lane's softmax row

    // Q fragment (B-operand of S^T mfma): n=l16 <-> m=mrow, k=s*32+quad*8+j
    f16x8 qf[2];
#pragma unroll
    for (int s = 0; s < 2; s++)
        qf[s] = *(const f16x8*)(qhp + (size_t)mrow * DD + s * 32 + quad * 8);

    // O accumulators, standard C-layout: o[v] rows m=w*16+quad*4+r, col d=16v+l16
    f32x4 o[4];
#pragma unroll
    for (int v = 0; v < 4; v++) o[v] = (f32x4)0.f;
    float m_run = -INFINITY, lacc = 0.f;

#pragma unroll 1
    for (int n0 = 0; n0 < TT; n0 += 64) {
        // mask: 4 b64 global loads for row mrow, kv = n0+16t+quad*4..+3
        f16x4 mk[4];
#pragma unroll
        for (int t = 0; t < 4; t++)
            mk[t] = *(const f16x4*)(mb + (size_t)mrow * TT + n0 + 16 * t + quad * 4);

        __syncthreads();   // prev-iter readers done with Ks/Vt
#pragma unroll
        for (int i = 0; i < 4; i++) {
            int u = tid + i * 128;
            int r = u >> 3, cp = u & 7;
            int c = cp ^ (r & 7);
            gload16(khp + (size_t)(n0 + r) * DD + c * 8, &Ks[u * 8]);
            gload16(vtp + (size_t)r * TT + n0 + c * 8,   &Vt[u * 8]);
        }
        __syncthreads();

        // S^T = K.Q^T : st[t] rows kv=16t+quad*4+r, col m=l16 (A-row = 16t+l16)
        f32x4 st[4];
#pragma unroll
        for (int t = 0; t < 4; t++) st[t] = (f32x4)0.f;
#pragma unroll
        for (int s = 0; s < 2; s++)
#pragma unroll
            for (int t = 0; t < 4; t++) {
                int R = 16 * t + l16;
                const f16x8 kf = *(const f16x8*)&Ks[(R * 8 + ((s * 4 + quad) ^ (R & 7))) * 8];
                st[t] = __builtin_amdgcn_mfma_f32_16x16x32_f16(kf, qf[s], st[t], 0, 0, 0);
            }
        // + mask
#pragma unroll
        for (int t = 0; t < 4; t++)
#pragma unroll
            for (int r = 0; r < 4; r++)
                st[t][r] += (float)mk[t][r];

        // softmax: this lane's 16 values all belong to row mrow
        float rm = st[0][0];
#pragma unroll
        for (int t = 0; t < 4; t++)
#pragma unroll
            for (int r = 0; r < 4; r++) rm = fmaxf(rm, st[t][r]);
        rm = fmaxf(rm, __shfl_xor(rm, 16));
        rm = fmaxf(rm, __shfl_xor(rm, 32));
        float mnew  = fmaxf(m_run, rm);
        float alpha = __expf(m_run - mnew);   // 0 on first iteration
        m_run = mnew;

        float ls = 0.f;
#pragma unroll
        for (int t = 0; t < 4; t++)
#pragma unroll
            for (int r = 0; r < 4; r++) {
                float p = __expf(st[t][r] - m_run);
                st[t][r] = p;
                ls += p;
            }
        lacc = lacc * alpha + ls;             // quad-partial; reduced in epilogue

        // rescale o: its rows are m=w*16+quad*4+r -> fetch alpha cross-quad
        float ar[4];
#pragma unroll
        for (int r = 0; r < 4; r++) ar[r] = __shfl(alpha, quad * 4 + r);
#pragma unroll
        for (int v = 0; v < 4; v++)
#pragma unroll
            for (int r = 0; r < 4; r++)
                o[v][r] *= ar[r];

        // P^T frag -> Ps[m][kv], 4 b64 writes (4 consecutive kv at fixed m);
        // per-wave-private strip, same-wave RAW ordered via lgkmcnt
#pragma unroll
        for (int t = 0; t < 4; t++) {
            f16x4 pk;
#pragma unroll
            for (int r = 0; r < 4; r++) pk[r] = (_Float16)st[t][r];
            *(f16x4*)&Ps[(w * 16 + l16) * 72 + 16 * t + quad * 4] = pk;
        }

        // O += P.V^T : A = P (b128 from own strip), B = V^T (b128, R=16v+l16)
#pragma unroll
        for (int s = 0; s < 2; s++) {
            const f16x8 pf = *(const f16x8*)&Ps[(w * 16 + l16) * 72 + s * 32 + quad * 8];
#pragma unroll
            for (int v = 0; v < 4; v++) {
                int R = 16 * v + l16;
                const f16x8 vf = *(const f16x8*)&Vt[(R * 8 + ((s * 4 + quad) ^ (R & 7))) * 8];
                o[v] = __builtin_amdgcn_mfma_f32_16x16x32_f16(pf, vf, o[v], 0, 0, 0);
            }
        }
    }

    // finish row sums across quads, distribute inverse to o's rows
    lacc += __shfl_xor(lacc, 16);
    lacc += __shfl_xor(lacc, 32);
    float linv = 1.0f / lacc;
    float invr[4];
#pragma unroll
    for (int r = 0; r < 4; r++) invr[r] = __shfl(linv, quad * 4 + r);

    // epilogue: ctx_hi [B,T,E] fp16 (row m=w*16+quad*4+r, col d=16v+l16)
#pragma unroll
    for (int r = 0; r < 4; r++) {
        int m = m0 + w * 16 + quad * 4 + r;
        size_t base = (size_t)(b * TT + m) * EE + h * DD;
#pragma unroll
        for (int v = 0; v < 4; v++)
            ctxh[base + 16 * v + l16] = f2h(o[v][r] * invr[r]);
    }
}

// ---------------------------------------------------------------------------
extern "C" void kernel_launch(void* const* d_in, const int* in_sizes, int n_in,
                              void* d_out, int out_size, void* d_ws, size_t ws_size,
                              hipStream_t stream)
{
    const float* hs   = (const float*)d_in[0];
    const float* mask = (const float*)d_in[1];
    const float* Wq   = (const float*)d_in[2];
    const float* bq   = (const float*)d_in[3];
    const float* Wk   = (const float*)d_in[4];
    const float* bk   = (const float*)d_in[5];
    const float* Wv   = (const float*)d_in[6];
    const float* bv   = (const float*)d_in[7];
    const float* Wo   = (const float*)d_in[8];
    const float* bo   = (const float*)d_in[9];
    float* out = (float*)d_out;

    unsigned short* ws    = (unsigned short*)d_ws;
    unsigned short* hsp   = ws;                                 // fp16 hs (-> ctx_hi)
    unsigned short* wqp   = ws + (size_t)N_HS;                  // wq,wk,wv,wo
    unsigned short* wop   = wqp + 3 * (size_t)N_W;
    unsigned short* qkvb  = wqp + 4 * (size_t)N_W;              // q, k, v
    unsigned short* qp    = qkvb;
    unsigned short* kp    = qp + (size_t)NQKV;
    unsigned short* vp    = kp + (size_t)NQKV;
    unsigned short* vtp   = vp + (size_t)NQKV;                  // V^T [B,H,D,T]
    unsigned short* maskh = vtp + (size_t)NQKV;
    unsigned short* ctxh  = ws;                                 // alias hs (dead after qkv)

    split_kernel<<<12288, 256, 0, stream>>>(hs, Wq, Wk, Wv, Wo, mask, ws, maskh);
    qkv_kernel<<<dim3(24, 32), 256, 0, stream>>>(hsp, wqp, bq, bk, bv, qkvb);
    vtrans_kernel<<<dim3(TT / 64, BB * HH), 256, 0, stream>>>(vp, vtp);
    attn_kernel<<<dim3(BB * HH, TT / 32), 128, 0, stream>>>(qp, kp, vtp, maskh, ctxh);
    outproj_kernel<<<dim3(8, 64), 256, 0, stream>>>(ctxh, wop, bo, out);
}